// Round 12
// baseline (40.295 us; speedup 1.0000x reference)
//
#include <hip/hip_runtime.h>
#include <math.h>

// Batched tridiagonal solve A(exp(alpha)) u = f_rhs via chunked partition
// (SPIKE-style), ONE row per wave (max wave count = max latency hiding).
// Round 12: occupancy attack. r9/r11 showed the kernel is exposed-latency
// bound (~3000 stall cy/wave, 2-3 resident waves/SIMD). Changes:
//  - back to 1 row/wave, CS=16 (16384 waves = 16/SIMD of schedulable work)
//  - r8 algebra: cA/uA/vA -> (B,D,A) transform crosses the f64 scan; phase 3
//    is pure 2-fma recovery (no re-solve, no LDS reads, no rcp). Passed 3x
//    at absmax 4.8828e-4 deterministically.
//  - WPB=8 (512-thread blocks): f_lds amortized 8 ways; LDS 38KB/block ->
//    4 blocks/CU -> 32-wave ceiling.
//  - launch_bounds(512,6): VGPR cap ~85 >= ~80-reg scan-time live set, so
//    the allocator has room to keep the arrays in registers (r6/r8 chose
//    44-48 and spilled).
//  - ostage drain ordered by wave-local s_waitcnt lgkmcnt(0) (per-wave
//    buffer, in-order DS) instead of a block barrier.

constexpr int BT   = 16384;
constexpr int MPTS = 1024;
constexpr int NU   = 1023;   // real unknowns
constexpr int CS   = 16;     // chunk size (per lane)
constexpr int WPB  = 8;      // waves (rows) per block

__device__ __forceinline__ float frcp(float x) {
    float r = __builtin_amdgcn_rcpf(x);        // v_rcp_f32
    r = fmaf(r, fmaf(-x, r, 1.0f), r);         // 1 NR -> ~0.5 ulp
    return r;
}
__device__ __forceinline__ double drcp(double x) {
    double r = __builtin_amdgcn_rcp(x);        // v_rcp_f64, ~2^-27
    r = fma(r, fma(-x, r, 1.0), r);            // 1 NR -> ~2^-54
    return r;
}
__device__ __forceinline__ int sw(int j) { return j + (j >> 5); }

__global__ __launch_bounds__(WPB * 64, 6)
void pt_kernel(const float* __restrict__ alpha,
               const float* __restrict__ f_rhs,
               float* __restrict__ out) {
    const int t    = threadIdx.x;
    const int lane = t & 63;
    const int w    = t >> 6;
    const int row  = blockIdx.x * WPB + w;
    const int s    = lane * CS;          // first global index of this chunk

    __shared__ float f_lds[1056];            // swizzled: h2*f[j] at sw(j)
    __shared__ float ostage[WPB][1056];      // per-wave output stage

    const float h2 = (float)(1.0 / (1023.0 * 1023.0));
    for (int i = t; i < NU; i += WPB * 64) f_lds[sw(i)] = h2 * f_rhs[i];
    if (t == 0) f_lds[sw(1023)] = 0.0f;      // identity-pad row: f = 0

    // ---------------- load K = exp(alpha) for this chunk (17 values) --------
    const float* arow = alpha + (size_t)row * MPTS;
    float kf[CS + 1];
    #pragma unroll
    for (int q = 0; q < 4; ++q) {
        const float4 v = *reinterpret_cast<const float4*>(arow + s + 4 * q);
        kf[4 * q + 0] = expf(v.x);
        kf[4 * q + 1] = expf(v.y);
        kf[4 * q + 2] = expf(v.z);
        kf[4 * q + 3] = expf(v.w);
    }
    {
        float kx = (lane < 63) ? arow[s + CS] : 0.0f;  // lane63: exp(0)=1
        kf[CS] = expf(kx);
    }
    // lane 63 pre-patch: kn at j=1022 -> 0 gives b=kc, d=0 there; at j=1023
    // kc=0, kn=1 gives the identity row (b=1) with f=0.
    if (lane == 63) kf[15] = 0.0f;

    __syncthreads();  // f_lds ready

    // ---------------- phase 1a: in-chunk forward elimination (f32) ----------
    float cA[CS], uA[CS], vA[CS];
    {
        // cp_init = 1 for lane 0 folds the j=0 boundary (den = 2*K0 + K1).
        float cp = (lane == 0) ? 1.0f : 0.0f;
        float up = 0.0f, vp = 1.0f;
        #pragma unroll
        for (int i = 0; i < CS; ++i) {
            const int j = s + i;
            const float kc = kf[i];
            const float kn = kf[i + 1];
            const float b  = kc + kn;
            const float f  = f_lds[sw(j)];
            const float den = fmaf(kc, cp, b);
            const float r   = frcp(den);
            float ci = -kn * r;
            const float ui = fmaf(kc, up, f) * r;
            const float vi = (kc * vp) * r;
            if (i == CS - 1) ci = (lane == 63) ? 0.0f : ci;  // identity pad row
            cA[i] = ci; uA[i] = ui; vA[i] = vi;
            cp = ci; up = ui; vp = vi;
        }
    }

    // ---------------- phase 1b: back-substitution transform (f32) -----------
    // u_i = D_i + A_i * uL + B_i * uR   (in place: uA=D, vA=A, cA=B)
    float De_f, Ae_f, Be_f, Ds_f, As_f, Bs_f;
    {
        float Dn = uA[CS - 1], An = vA[CS - 1], Bn = -cA[CS - 1];
        De_f = Dn; Ae_f = An; Be_f = Bn;
        uA[CS - 1] = Dn; vA[CS - 1] = An; cA[CS - 1] = Bn;
        #pragma unroll
        for (int i = CS - 2; i >= 0; --i) {
            const float ci = cA[i];
            Dn = fmaf(-ci, Dn, uA[i]);
            An = fmaf(-ci, An, vA[i]);
            Bn = -ci * Bn;
            uA[i] = Dn; vA[i] = An; cA[i] = Bn;
        }
        Ds_f = uA[0]; As_f = vA[0]; Bs_f = cA[0];
    }

    // ---------------- phase 2: reduced boundary system (f64) ----------------
    // y_p = Ds + As*x_{p-1} + Bs*y_{p+1};  x_p = De + Ae*x_{p-1} + Be*y_{p+1}
    // Projective 3x3 suffix scan, kept normalized so m22 == 1 (6 entries).
    const double Ds = (double)Ds_f, As = (double)As_f, Bs = (double)Bs_f;
    const double De = (double)De_f, Ae = (double)Ae_f, Be = (double)Be_f;
    double m00 = Bs;
    double m01 = fma(Bs, De, -(Ds * Be));
    double m02 = Ds;
    double m11 = fma(Bs, Ae, -(As * Be));
    double m12 = As;
    double m21 = -Be;

    #pragma unroll
    for (int dlt = 1; dlt < 64; dlt <<= 1) {
        const bool val = (lane + dlt) < 64;
        double b00 = __shfl_down(m00, dlt); b00 = val ? b00 : 1.0;
        double b01 = __shfl_down(m01, dlt); b01 = val ? b01 : 0.0;
        double b02 = __shfl_down(m02, dlt); b02 = val ? b02 : 0.0;
        double b11 = __shfl_down(m11, dlt); b11 = val ? b11 : 1.0;
        double b12 = __shfl_down(m12, dlt); b12 = val ? b12 : 0.0;
        double b21 = __shfl_down(m21, dlt); b21 = val ? b21 : 0.0;
        const double n00 = m00 * b00;
        const double n01 = fma(m00, b01, fma(m01, b11, m02 * b21));
        const double n02 = fma(m00, b02, fma(m01, b12, m02));   // b22 == 1
        const double n11 = fma(m11, b11, m12 * b21);
        const double n12 = fma(m11, b12, m12);
        const double n21 = fma(m21, b11, b21);                  // m22 == 1
        const double n22 = fma(m21, b12, 1.0);
        const double rn = drcp(n22);       // n22 in (0,1]: strict dominance
        m00 = n00 * rn; m01 = n01 * rn; m02 = n02 * rn;
        m11 = n11 * rn; m12 = n12 * rn; m21 = n21 * rn;
    }
    // y_p = alf + bet * x_{p-1}   (m22 == 1)
    const double alf = m02;
    const double bet = m12;
    double alfn = __shfl_down(alf, 1); alfn = (lane == 63) ? 0.0 : alfn;
    double betn = __shfl_down(bet, 1); betn = (lane == 63) ? 0.0 : betn;

    // x_p = dl + gm * x_{p-1}
    const double tt = drcp(fma(-Be, betn, 1.0));
    const double dl = fma(Be, alfn, De) * tt;
    const double gm = Ae * tt;

    // Affine prefix scan for x (x_{-1} = 0).
    double X = dl, G = gm;
    #pragma unroll
    for (int dlt = 1; dlt < 64; dlt <<= 1) {
        double bx = __shfl_up(X, dlt);
        double bg = __shfl_up(G, dlt);
        const bool val = lane >= dlt;
        bx = val ? bx : 0.0;
        bg = val ? bg : 1.0;
        X = fma(G, bx, X);
        G = G * bg;
    }
    double xp = __shfl_up(X, 1);
    const double uLd = (lane == 0) ? 0.0 : xp;          // u_{s-1}
    const double Y   = fma(bet, uLd, alf);              // y_p = u_s
    double yn = __shfl_down(Y, 1);
    const double uRd = (lane == 63) ? 0.0 : yn;         // u_{e+1}

    // ---------------- phase 3: 2-fma recovery + staged write (f32) ----------
    const float uL = (float)uLd;
    const float uR = (float)uRd;
    float* ost = ostage[w];
    #pragma unroll
    for (int i = 0; i < CS; ++i) {
        const float uu = fmaf(vA[i], uL, fmaf(cA[i], uR, uA[i]));
        ost[sw(s + i)] = uu;               // lane63 i=15 writes pad j=1023: ok
    }
    // ostage[w] is wave-private; DS ops are in-order per wave. lgkmcnt(0)
    // orders write -> read without an 8-wave block barrier.
    asm volatile("s_waitcnt lgkmcnt(0)" ::: "memory");

    // Coalesced output: 64 lanes x 4B contiguous per instruction.
    float* orow = out + (size_t)row * NU;
    #pragma unroll
    for (int it = 0; it < 16; ++it) {
        const int c = it * 64 + lane;
        if (c < NU) orow[c] = ost[sw(c)];
    }
}

extern "C" void kernel_launch(void* const* d_in, const int* in_sizes, int n_in,
                              void* d_out, int out_size, void* d_ws, size_t ws_size,
                              hipStream_t stream) {
    const float* alpha = (const float*)d_in[0];
    const float* f_rhs = (const float*)d_in[1];
    float* out = (float*)d_out;

    dim3 grid(BT / WPB), block(WPB * 64);
    pt_kernel<<<grid, block, 0, stream>>>(alpha, f_rhs, out);
}